// Round 1
// baseline (15167.155 us; speedup 1.0000x reference)
//
#include <hip/hip_runtime.h>
#include <math.h>

#define N_NODES 100000
#define E_EDGES 1600000
#define ETOT (E_EDGES + N_NODES)   // 1,700,000 with self-loops appended
#define NEG 0.2f

// ---- order-preserving float<->uint map for atomicMax on floats ----
__device__ __forceinline__ unsigned fmap(float f) {
  unsigned u = __float_as_uint(f);
  return (u & 0x80000000u) ? ~u : (u | 0x80000000u);
}
__device__ __forceinline__ float funmap(unsigned m) {
  return (m & 0x80000000u) ? __uint_as_float(m & 0x7fffffffu) : __uint_as_float(~m);
}

__device__ __forceinline__ float lrelu(float v) { return v > 0.f ? v : NEG * v; }
__device__ __forceinline__ float elu(float v) { return v > 0.f ? v : (expf(v) - 1.f); }

// ---------- GEMM1: x[N,128] @ W1l,W1r[128,128] (+bias) -> xl1, xr1 ----------
__global__ __launch_bounds__(256) void gemm1_kernel(
    const float* __restrict__ x,
    const float* __restrict__ Wl, const float* __restrict__ bl,
    const float* __restrict__ Wr, const float* __restrict__ br,
    float* __restrict__ xl, float* __restrict__ xr) {
  __shared__ __align__(16) float xs[8][128];
  int t = threadIdx.x;
  int base = blockIdx.x * 8;
  for (int idx = t; idx < 8 * 128; idx += 256) {
    int r = idx >> 7, k = idx & 127;
    int row = base + r;
    xs[r][k] = (row < N_NODES) ? x[(size_t)row * 128 + k] : 0.f;
  }
  __syncthreads();
  const float* W = (t < 128) ? Wl : Wr;
  float* o = (t < 128) ? xl : xr;
  int col = t & 127;
  float bv = (t < 128) ? bl[col] : br[col];
  float acc[8];
#pragma unroll
  for (int r = 0; r < 8; r++) acc[r] = bv;
  for (int k4 = 0; k4 < 128; k4 += 4) {
    float w0 = W[(k4 + 0) * 128 + col];
    float w1 = W[(k4 + 1) * 128 + col];
    float w2 = W[(k4 + 2) * 128 + col];
    float w3 = W[(k4 + 3) * 128 + col];
#pragma unroll
    for (int r = 0; r < 8; r++) {
      float4 xv = *reinterpret_cast<const float4*>(&xs[r][k4]);
      acc[r] += xv.x * w0 + xv.y * w1 + xv.z * w2 + xv.w * w3;
    }
  }
#pragma unroll
  for (int r = 0; r < 8; r++) {
    int row = base + r;
    if (row < N_NODES) o[(size_t)row * 128 + col] = acc[r];
  }
}

// ---------- L1 edge scores + segment max ----------
__global__ __launch_bounds__(256) void l1_score_kernel(
    const float* __restrict__ xl, const float* __restrict__ xr,
    const int* __restrict__ ei, const float* __restrict__ att,
    float* __restrict__ S, unsigned* __restrict__ Mm) {
  int e = blockIdx.x * blockDim.x + threadIdx.x;
  if (e >= ETOT) return;
  int src, dst;
  if (e < E_EDGES) { src = ei[e]; dst = ei[E_EDGES + e]; }
  else { src = e - E_EDGES; dst = src; }
  const float4* pl = reinterpret_cast<const float4*>(xl + (size_t)src * 128);
  const float4* pr = reinterpret_cast<const float4*>(xr + (size_t)dst * 128);
  const float4* pa = reinterpret_cast<const float4*>(att);
#pragma unroll
  for (int h = 0; h < 4; h++) {
    float sc = 0.f;
#pragma unroll
    for (int q = 0; q < 8; q++) {
      float4 a = pl[h * 8 + q];
      float4 b = pr[h * 8 + q];
      float4 at = pa[h * 8 + q];
      sc += at.x * lrelu(a.x + b.x);
      sc += at.y * lrelu(a.y + b.y);
      sc += at.z * lrelu(a.z + b.z);
      sc += at.w * lrelu(a.w + b.w);
    }
    S[(size_t)e * 4 + h] = sc;
    atomicMax(&Mm[dst * 4 + h], fmap(sc));
  }
}

// ---------- L1 exp + denom + weighted scatter-accumulate ----------
__global__ __launch_bounds__(256) void l1_accum_kernel(
    const float* __restrict__ xl, const int* __restrict__ ei,
    const float* __restrict__ S, const unsigned* __restrict__ Mm,
    float* __restrict__ Dn, float* __restrict__ acc) {
  int e = blockIdx.x * blockDim.x + threadIdx.x;
  if (e >= ETOT) return;
  int src, dst;
  if (e < E_EDGES) { src = ei[e]; dst = ei[E_EDGES + e]; }
  else { src = e - E_EDGES; dst = src; }
#pragma unroll
  for (int h = 0; h < 4; h++) {
    float m = funmap(Mm[dst * 4 + h]);
    float ex = expf(S[(size_t)e * 4 + h] - m);
    atomicAdd(&Dn[dst * 4 + h], ex);
    const float* xsrc = xl + (size_t)src * 128 + h * 32;
    float* ad = acc + (size_t)dst * 128 + h * 32;
#pragma unroll
    for (int c = 0; c < 32; c++) atomicAdd(&ad[c], ex * xsrc[c]);
  }
}

// ---------- L1 finalize: h1 = elu(acc/denom + bias) ----------
__global__ __launch_bounds__(256) void l1_final_kernel(
    const float* __restrict__ acc, const float* __restrict__ Dn,
    const float* __restrict__ bias, float* __restrict__ h1) {
  int i = blockIdx.x * blockDim.x + threadIdx.x;
  if (i >= N_NODES * 128) return;
  int node = i >> 7, o = i & 127, h = o >> 5;
  float v = acc[i] / Dn[node * 4 + h] + bias[o];
  h1[i] = elu(v);
}

// ---------- GEMM2: h1[N,128] @ W2l,W2r[128,32] (+bias) -> xl2, xr2 ----------
__global__ __launch_bounds__(256) void gemm2_kernel(
    const float* __restrict__ h1,
    const float* __restrict__ Wl, const float* __restrict__ bl,
    const float* __restrict__ Wr, const float* __restrict__ br,
    float* __restrict__ xl2, float* __restrict__ xr2) {
  __shared__ __align__(16) float xs[4][128];
  int t = threadIdx.x;
  int base = blockIdx.x * 4;
  for (int idx = t; idx < 4 * 128; idx += 256) {
    int r = idx >> 7, k = idx & 127;
    int row = base + r;
    xs[r][k] = (row < N_NODES) ? h1[(size_t)row * 128 + k] : 0.f;
  }
  __syncthreads();
  int r = t >> 6, c6 = t & 63;
  bool isL = c6 < 32;
  int col = c6 & 31;
  const float* W = isL ? Wl : Wr;
  float acc = isL ? bl[col] : br[col];
  for (int k4 = 0; k4 < 128; k4 += 4) {
    float4 xv = *reinterpret_cast<const float4*>(&xs[r][k4]);
    acc += xv.x * W[(k4 + 0) * 32 + col] + xv.y * W[(k4 + 1) * 32 + col]
         + xv.z * W[(k4 + 2) * 32 + col] + xv.w * W[(k4 + 3) * 32 + col];
  }
  int row = base + r;
  if (row < N_NODES) (isL ? xl2 : xr2)[(size_t)row * 32 + col] = acc;
}

// ---------- L2 edge scores + segment max (1 head) ----------
__global__ __launch_bounds__(256) void l2_score_kernel(
    const float* __restrict__ xl2, const float* __restrict__ xr2,
    const int* __restrict__ ei, const float* __restrict__ att,
    float* __restrict__ S, unsigned* __restrict__ Mm) {
  int e = blockIdx.x * blockDim.x + threadIdx.x;
  if (e >= ETOT) return;
  int src, dst;
  if (e < E_EDGES) { src = ei[e]; dst = ei[E_EDGES + e]; }
  else { src = e - E_EDGES; dst = src; }
  const float4* pl = reinterpret_cast<const float4*>(xl2 + (size_t)src * 32);
  const float4* pr = reinterpret_cast<const float4*>(xr2 + (size_t)dst * 32);
  const float4* pa = reinterpret_cast<const float4*>(att);
  float sc = 0.f;
#pragma unroll
  for (int q = 0; q < 8; q++) {
    float4 a = pl[q];
    float4 b = pr[q];
    float4 at = pa[q];
    sc += at.x * lrelu(a.x + b.x);
    sc += at.y * lrelu(a.y + b.y);
    sc += at.z * lrelu(a.z + b.z);
    sc += at.w * lrelu(a.w + b.w);
  }
  S[e] = sc;
  atomicMax(&Mm[dst], fmap(sc));
}

// ---------- L2 exp + denom + weighted scatter-accumulate ----------
__global__ __launch_bounds__(256) void l2_accum_kernel(
    const float* __restrict__ xl2, const int* __restrict__ ei,
    const float* __restrict__ S, const unsigned* __restrict__ Mm,
    float* __restrict__ Dn, float* __restrict__ acc) {
  int e = blockIdx.x * blockDim.x + threadIdx.x;
  if (e >= ETOT) return;
  int src, dst;
  if (e < E_EDGES) { src = ei[e]; dst = ei[E_EDGES + e]; }
  else { src = e - E_EDGES; dst = src; }
  float m = funmap(Mm[dst]);
  float ex = expf(S[e] - m);
  atomicAdd(&Dn[dst], ex);
  const float* xsrc = xl2 + (size_t)src * 32;
  float* ad = acc + (size_t)dst * 32;
#pragma unroll
  for (int c = 0; c < 32; c++) atomicAdd(&ad[c], ex * xsrc[c]);
}

// ---------- finalize: out = elu(acc2/denom + bias2) @ Wlin + blin ----------
__global__ __launch_bounds__(256) void final_kernel(
    const float* __restrict__ acc2, const float* __restrict__ Dn,
    const float* __restrict__ bias2, const float* __restrict__ Wlin,
    const float* __restrict__ blin, float* __restrict__ out) {
  int i = blockIdx.x * blockDim.x + threadIdx.x;
  if (i >= N_NODES) return;
  float d = Dn[i];
  float o0 = blin[0], o1 = blin[1];
#pragma unroll
  for (int c = 0; c < 32; c++) {
    float v = elu(acc2[(size_t)i * 32 + c] / d + bias2[c]);
    o0 += v * Wlin[c * 2 + 0];
    o1 += v * Wlin[c * 2 + 1];
  }
  out[(size_t)i * 2 + 0] = o0;
  out[(size_t)i * 2 + 1] = o1;
}

extern "C" void kernel_launch(void* const* d_in, const int* in_sizes, int n_in,
                              void* d_out, int out_size, void* d_ws, size_t ws_size,
                              hipStream_t stream) {
  const float* x     = (const float*)d_in[0];
  const int*   ei    = (const int*)d_in[1];
  const float* W1l   = (const float*)d_in[2];
  const float* b1l   = (const float*)d_in[3];
  const float* W1r   = (const float*)d_in[4];
  const float* b1r   = (const float*)d_in[5];
  const float* att1  = (const float*)d_in[6];
  const float* bias1 = (const float*)d_in[7];
  const float* W2l   = (const float*)d_in[8];
  const float* b2l   = (const float*)d_in[9];
  const float* W2r   = (const float*)d_in[10];
  const float* b2r   = (const float*)d_in[11];
  const float* att2  = (const float*)d_in[12];
  const float* bias2 = (const float*)d_in[13];
  const float* Wlin  = (const float*)d_in[14];
  const float* blin  = (const float*)d_in[15];
  float* out = (float*)d_out;

  // workspace layout (floats). Aliasing is safe given stream ordering:
  //   A: xl1 [N*128]            ; acc2 [N*32] aliases after l1_accum done
  //   B: xr1 [N*128]            ; h1 aliases after l1_score done
  //   C: acc1 [N*128]           ; xl2/xr2 [N*32 each] alias after l1_final done
  //   S: scores [ETOT*4]        ; layer2 uses first ETOT
  //   Mm: mapped max [N*4 u32]  ; layer2 uses first N
  //   Dn: denom [N*4]           ; layer2 uses first N
  float* A = (float*)d_ws;
  float* B = A + (size_t)N_NODES * 128;
  float* C = B + (size_t)N_NODES * 128;
  float* S = C + (size_t)N_NODES * 128;
  unsigned* Mm = (unsigned*)(S + (size_t)ETOT * 4);
  float* Dn = (float*)(Mm + (size_t)N_NODES * 4);

  float* xl1  = A;
  float* xr1  = B;
  float* acc1 = C;
  float* h1   = B;
  float* xl2  = C;
  float* xr2  = C + (size_t)N_NODES * 32;
  float* acc2 = A;

  // ---- layer 1 ----
  hipMemsetAsync(acc1, 0, (size_t)N_NODES * 128 * sizeof(float), stream);
  hipMemsetAsync(Mm, 0, (size_t)N_NODES * 4 * sizeof(unsigned), stream);
  hipMemsetAsync(Dn, 0, (size_t)N_NODES * 4 * sizeof(float), stream);
  gemm1_kernel<<<(N_NODES + 7) / 8, 256, 0, stream>>>(x, W1l, b1l, W1r, b1r, xl1, xr1);
  l1_score_kernel<<<(ETOT + 255) / 256, 256, 0, stream>>>(xl1, xr1, ei, att1, S, Mm);
  l1_accum_kernel<<<(ETOT + 255) / 256, 256, 0, stream>>>(xl1, ei, S, Mm, Dn, acc1);
  l1_final_kernel<<<(N_NODES * 128 + 255) / 256, 256, 0, stream>>>(acc1, Dn, bias1, h1);

  // ---- layer 2 ----
  hipMemsetAsync(acc2, 0, (size_t)N_NODES * 32 * sizeof(float), stream);
  hipMemsetAsync(Mm, 0, (size_t)N_NODES * sizeof(unsigned), stream);
  hipMemsetAsync(Dn, 0, (size_t)N_NODES * sizeof(float), stream);
  gemm2_kernel<<<(N_NODES + 3) / 4, 256, 0, stream>>>(h1, W2l, b2l, W2r, b2r, xl2, xr2);
  l2_score_kernel<<<(ETOT + 255) / 256, 256, 0, stream>>>(xl2, xr2, ei, att2, S, Mm);
  l2_accum_kernel<<<(ETOT + 255) / 256, 256, 0, stream>>>(xl2, ei, S, Mm, Dn, acc2);
  final_kernel<<<(N_NODES + 255) / 256, 256, 0, stream>>>(acc2, Dn, bias2, Wlin, blin, out);
}

// Round 2
// 745.929 us; speedup vs baseline: 20.3332x; 20.3332x over previous
//
#include <hip/hip_runtime.h>
#include <math.h>

#define N_NODES 100000
#define E_EDGES 1600000
#define ETOT (E_EDGES + N_NODES)   // 1,700,000 with self-loops appended
#define NEG 0.2f
#define NBLK ((N_NODES + 255) / 256)  // 391 scan blocks

__device__ __forceinline__ float lrelu(float v) { return v > 0.f ? v : NEG * v; }
__device__ __forceinline__ float elu(float v) { return v > 0.f ? v : (__expf(v) - 1.f); }

// ================= CSR build (by destination) =================
__global__ __launch_bounds__(256) void hist_kernel(const int* __restrict__ ei,
                                                   unsigned* __restrict__ deg) {
  int e = blockIdx.x * blockDim.x + threadIdx.x;
  if (e >= ETOT) return;
  int dst = (e < E_EDGES) ? ei[E_EDGES + e] : (e - E_EDGES);
  atomicAdd(&deg[dst], 1u);
}

// per-256-block exclusive scan of deg -> rowptr (local), block totals -> bsum
__global__ __launch_bounds__(256) void scan1_kernel(const unsigned* __restrict__ deg,
                                                    unsigned* __restrict__ rowptr,
                                                    unsigned* __restrict__ bsum) {
  __shared__ unsigned s[256];
  int t = threadIdx.x;
  int i = blockIdx.x * 256 + t;
  unsigned v = (i < N_NODES) ? deg[i] : 0u;
  s[t] = v;
  __syncthreads();
  for (int off = 1; off < 256; off <<= 1) {
    unsigned add = (t >= off) ? s[t - off] : 0u;
    __syncthreads();
    s[t] += add;
    __syncthreads();
  }
  if (i < N_NODES) rowptr[i] = s[t] - v;  // exclusive
  if (t == 255) bsum[blockIdx.x] = s[255];
}

// single-block exclusive scan of bsum[NBLK] (NBLK=391 <= 512)
__global__ __launch_bounds__(512) void scan2_kernel(unsigned* __restrict__ bsum) {
  __shared__ unsigned s[512];
  int t = threadIdx.x;
  unsigned v = (t < NBLK) ? bsum[t] : 0u;
  s[t] = v;
  __syncthreads();
  for (int off = 1; off < 512; off <<= 1) {
    unsigned add = (t >= off) ? s[t - off] : 0u;
    __syncthreads();
    s[t] += add;
    __syncthreads();
  }
  if (t < NBLK) bsum[t] = s[t] - v;  // exclusive
}

__global__ __launch_bounds__(256) void scan3_kernel(unsigned* __restrict__ rowptr,
                                                    const unsigned* __restrict__ bsum) {
  int i = blockIdx.x * 256 + threadIdx.x;
  if (i < N_NODES) rowptr[i] += bsum[blockIdx.x];
  if (i == 0) rowptr[N_NODES] = ETOT;
}

__global__ __launch_bounds__(256) void scatter_kernel(const int* __restrict__ ei,
                                                      const unsigned* __restrict__ rowptr,
                                                      unsigned* __restrict__ cursor,
                                                      int* __restrict__ csr_src) {
  int e = blockIdx.x * blockDim.x + threadIdx.x;
  if (e >= ETOT) return;
  int src, dst;
  if (e < E_EDGES) { src = ei[e]; dst = ei[E_EDGES + e]; }
  else { src = e - E_EDGES; dst = src; }
  unsigned pos = rowptr[dst] + atomicAdd(&cursor[dst], 1u);
  csr_src[pos] = src;
}

// ================= GEMM1: x[N,128] @ W1l,W1r[128,128] (+bias) -> xl1, xr1 =================
__global__ __launch_bounds__(256) void gemm1_kernel(
    const float* __restrict__ x,
    const float* __restrict__ Wl, const float* __restrict__ bl,
    const float* __restrict__ Wr, const float* __restrict__ br,
    float* __restrict__ xl, float* __restrict__ xr) {
  __shared__ __align__(16) float xs[8][128];
  int t = threadIdx.x;
  int base = blockIdx.x * 8;
  for (int idx = t; idx < 8 * 128; idx += 256) {
    int r = idx >> 7, k = idx & 127;
    int row = base + r;
    xs[r][k] = (row < N_NODES) ? x[(size_t)row * 128 + k] : 0.f;
  }
  __syncthreads();
  const float* W = (t < 128) ? Wl : Wr;
  float* o = (t < 128) ? xl : xr;
  int col = t & 127;
  float bv = (t < 128) ? bl[col] : br[col];
  float acc[8];
#pragma unroll
  for (int r = 0; r < 8; r++) acc[r] = bv;
  for (int k4 = 0; k4 < 128; k4 += 4) {
    float w0 = W[(k4 + 0) * 128 + col];
    float w1 = W[(k4 + 1) * 128 + col];
    float w2 = W[(k4 + 2) * 128 + col];
    float w3 = W[(k4 + 3) * 128 + col];
#pragma unroll
    for (int r = 0; r < 8; r++) {
      float4 xv = *reinterpret_cast<const float4*>(&xs[r][k4]);
      acc[r] += xv.x * w0 + xv.y * w1 + xv.z * w2 + xv.w * w3;
    }
  }
#pragma unroll
  for (int r = 0; r < 8; r++) {
    int row = base + r;
    if (row < N_NODES) o[(size_t)row * 128 + col] = acc[r];
  }
}

// ================= L1 fused gather: score + online softmax + accum + ELU =================
// one wave per node; lane owns channels (2*lane, 2*lane+1); head = lane>>4
__global__ __launch_bounds__(256) void l1_gather_kernel(
    const float* __restrict__ xl, const float* __restrict__ xr,
    const int* __restrict__ csr_src, const unsigned* __restrict__ rowptr,
    const float* __restrict__ att, const float* __restrict__ bias,
    float* __restrict__ h1) {
  int wid = threadIdx.x >> 6;
  int lane = threadIdx.x & 63;
  int n = blockIdx.x * 4 + wid;
  if (n >= N_NODES) return;
  int c0 = lane * 2;
  float2 rv = *reinterpret_cast<const float2*>(xr + (size_t)n * 128 + c0);
  float2 av = *reinterpret_cast<const float2*>(att + c0);
  float bv0 = bias[c0], bv1 = bias[c0 + 1];
  float m = -1e30f, d = 0.f, acc0 = 0.f, acc1 = 0.f;
  unsigned beg = rowptr[n], end = rowptr[n + 1];
  for (unsigned i = beg; i < end; i++) {
    int s = csr_src[i];
    float2 a = *reinterpret_cast<const float2*>(xl + (size_t)s * 128 + c0);
    float v = av.x * lrelu(a.x + rv.x) + av.y * lrelu(a.y + rv.y);
    // reduce over the 16-lane head group -> per-head score
    v += __shfl_xor(v, 1);
    v += __shfl_xor(v, 2);
    v += __shfl_xor(v, 4);
    v += __shfl_xor(v, 8);
    float nm = fmaxf(m, v);
    float scale = __expf(m - nm);
    float p = __expf(v - nm);
    d = d * scale + p;
    acc0 = acc0 * scale + p * a.x;
    acc1 = acc1 * scale + p * a.y;
    m = nm;
  }
  float inv = 1.f / d;
  float2 res;
  res.x = elu(acc0 * inv + bv0);
  res.y = elu(acc1 * inv + bv1);
  *reinterpret_cast<float2*>(h1 + (size_t)n * 128 + c0) = res;
}

// ================= GEMM2: h1[N,128] @ W2l,W2r[128,32] (+bias) -> xl2, xr2 =================
__global__ __launch_bounds__(256) void gemm2_kernel(
    const float* __restrict__ h1,
    const float* __restrict__ Wl, const float* __restrict__ bl,
    const float* __restrict__ Wr, const float* __restrict__ br,
    float* __restrict__ xl2, float* __restrict__ xr2) {
  __shared__ __align__(16) float xs[4][128];
  int t = threadIdx.x;
  int base = blockIdx.x * 4;
  for (int idx = t; idx < 4 * 128; idx += 256) {
    int r = idx >> 7, k = idx & 127;
    int row = base + r;
    xs[r][k] = (row < N_NODES) ? h1[(size_t)row * 128 + k] : 0.f;
  }
  __syncthreads();
  int r = t >> 6, c6 = t & 63;
  bool isL = c6 < 32;
  int col = c6 & 31;
  const float* W = isL ? Wl : Wr;
  float acc = isL ? bl[col] : br[col];
  for (int k4 = 0; k4 < 128; k4 += 4) {
    float4 xv = *reinterpret_cast<const float4*>(&xs[r][k4]);
    acc += xv.x * W[(k4 + 0) * 32 + col] + xv.y * W[(k4 + 1) * 32 + col]
         + xv.z * W[(k4 + 2) * 32 + col] + xv.w * W[(k4 + 3) * 32 + col];
  }
  int row = base + r;
  if (row < N_NODES) (isL ? xl2 : xr2)[(size_t)row * 32 + col] = acc;
}

// ================= L2 fused gather + final linear =================
// one wave per node; lane&31 owns one channel; two edges per iteration (halves)
__global__ __launch_bounds__(256) void l2_gather_kernel(
    const float* __restrict__ xl2, const float* __restrict__ xr2,
    const int* __restrict__ csr_src, const unsigned* __restrict__ rowptr,
    const float* __restrict__ att, const float* __restrict__ bias,
    const float* __restrict__ Wlin, const float* __restrict__ blin,
    float* __restrict__ out) {
  int wid = threadIdx.x >> 6;
  int lane = threadIdx.x & 63;
  int n = blockIdx.x * 4 + wid;
  if (n >= N_NODES) return;
  int half = lane >> 5;
  int c = lane & 31;
  float rv = xr2[(size_t)n * 32 + c];
  float avv = att[c];
  float m = -1e30f, d = 0.f, acc = 0.f;
  unsigned beg = rowptr[n], end = rowptr[n + 1];
  for (unsigned i = beg + half; i < end; i += 2) {
    int s = csr_src[i];
    float a = xl2[(size_t)s * 32 + c];
    float v = avv * lrelu(a + rv);
    v += __shfl_xor(v, 1);
    v += __shfl_xor(v, 2);
    v += __shfl_xor(v, 4);
    v += __shfl_xor(v, 8);
    v += __shfl_xor(v, 16);
    float nm = fmaxf(m, v);
    float scale = __expf(m - nm);
    float p = __expf(v - nm);
    d = d * scale + p;
    acc = acc * scale + p * a;
    m = nm;
  }
  // merge the two halves' online-softmax states
  float mo = __shfl_xor(m, 32);
  float d_o = __shfl_xor(d, 32);
  float a_o = __shfl_xor(acc, 32);
  float M = fmaxf(m, mo);
  float es = __expf(m - M), eo = __expf(mo - M);
  d = d * es + d_o * eo;
  acc = acc * es + a_o * eo;
  float v = elu(acc / d + bias[c]);
  // fused final linear: out[n, 0..1]
  float o0 = v * Wlin[c * 2 + 0];
  float o1 = v * Wlin[c * 2 + 1];
#pragma unroll
  for (int msk = 1; msk <= 16; msk <<= 1) {
    o0 += __shfl_xor(o0, msk);
    o1 += __shfl_xor(o1, msk);
  }
  if (lane == 0) {
    out[(size_t)n * 2 + 0] = o0 + blin[0];
    out[(size_t)n * 2 + 1] = o1 + blin[1];
  }
}

extern "C" void kernel_launch(void* const* d_in, const int* in_sizes, int n_in,
                              void* d_out, int out_size, void* d_ws, size_t ws_size,
                              hipStream_t stream) {
  const float* x     = (const float*)d_in[0];
  const int*   ei    = (const int*)d_in[1];
  const float* W1l   = (const float*)d_in[2];
  const float* b1l   = (const float*)d_in[3];
  const float* W1r   = (const float*)d_in[4];
  const float* b1r   = (const float*)d_in[5];
  const float* att1  = (const float*)d_in[6];
  const float* bias1 = (const float*)d_in[7];
  const float* W2l   = (const float*)d_in[8];
  const float* b2l   = (const float*)d_in[9];
  const float* W2r   = (const float*)d_in[10];
  const float* b2r   = (const float*)d_in[11];
  const float* att2  = (const float*)d_in[12];
  const float* bias2 = (const float*)d_in[13];
  const float* Wlin  = (const float*)d_in[14];
  const float* blin  = (const float*)d_in[15];
  float* out = (float*)d_out;

  // workspace layout (fp32 unless noted):
  //   A: xl1 [N*128]  (later xl2 [N*32] + xr2 [N*32])
  //   B: xr1 [N*128]
  //   C: h1  [N*128]
  //   csr_src [ETOT] int
  //   rowptr [N+1] u32, deg/cursor [N] u32, bsum [512] u32
  float* A = (float*)d_ws;
  float* B = A + (size_t)N_NODES * 128;
  float* C = B + (size_t)N_NODES * 128;
  int* csr_src = (int*)(C + (size_t)N_NODES * 128);
  unsigned* rowptr = (unsigned*)(csr_src + (size_t)ETOT);
  unsigned* deg = rowptr + (N_NODES + 1);
  unsigned* cursor = deg + N_NODES;
  unsigned* bsum = cursor + N_NODES;

  float* xl1 = A;
  float* xr1 = B;
  float* h1  = C;
  float* xl2 = A;
  float* xr2 = A + (size_t)N_NODES * 32;

  // ---- CSR build (shared by both layers) ----
  hipMemsetAsync(deg, 0, (size_t)N_NODES * sizeof(unsigned), stream);
  hipMemsetAsync(cursor, 0, (size_t)N_NODES * sizeof(unsigned), stream);
  hist_kernel<<<(ETOT + 255) / 256, 256, 0, stream>>>(ei, deg);
  scan1_kernel<<<NBLK, 256, 0, stream>>>(deg, rowptr, bsum);
  scan2_kernel<<<1, 512, 0, stream>>>(bsum);
  scan3_kernel<<<NBLK, 256, 0, stream>>>(rowptr, bsum);
  scatter_kernel<<<(ETOT + 255) / 256, 256, 0, stream>>>(ei, rowptr, cursor, csr_src);

  // ---- layer 1 ----
  gemm1_kernel<<<(N_NODES + 7) / 8, 256, 0, stream>>>(x, W1l, b1l, W1r, b1r, xl1, xr1);
  l1_gather_kernel<<<(N_NODES + 3) / 4, 256, 0, stream>>>(xl1, xr1, csr_src, rowptr,
                                                          att1, bias1, h1);

  // ---- layer 2 + final linear ----
  gemm2_kernel<<<(N_NODES + 3) / 4, 256, 0, stream>>>(h1, W2l, b2l, W2r, b2r, xl2, xr2);
  l2_gather_kernel<<<(N_NODES + 3) / 4, 256, 0, stream>>>(xl2, xr2, csr_src, rowptr,
                                                          att2, bias2, Wlin, blin, out);
}

// Round 3
// 624.770 us; speedup vs baseline: 24.2764x; 1.1939x over previous
//
#include <hip/hip_runtime.h>
#include <hip/hip_fp16.h>
#include <math.h>

#define N_NODES 100000
#define E_EDGES 1600000
#define ETOT (E_EDGES + N_NODES)   // 1,700,000 with self-loops appended
#define NEG 0.2f
#define NBLK ((N_NODES + 255) / 256)  // 391 scan blocks

__device__ __forceinline__ float lrelu(float v) { return v > 0.f ? v : NEG * v; }
__device__ __forceinline__ float elu(float v) { return v > 0.f ? v : (__expf(v) - 1.f); }

// ================= CSR build (by destination) =================
__global__ __launch_bounds__(256) void hist_kernel(const int* __restrict__ ei,
                                                   unsigned* __restrict__ deg) {
  int e = blockIdx.x * blockDim.x + threadIdx.x;
  if (e >= ETOT) return;
  int dst = (e < E_EDGES) ? ei[E_EDGES + e] : (e - E_EDGES);
  atomicAdd(&deg[dst], 1u);
}

__global__ __launch_bounds__(256) void scan1_kernel(const unsigned* __restrict__ deg,
                                                    unsigned* __restrict__ rowptr,
                                                    unsigned* __restrict__ bsum) {
  __shared__ unsigned s[256];
  int t = threadIdx.x;
  int i = blockIdx.x * 256 + t;
  unsigned v = (i < N_NODES) ? deg[i] : 0u;
  s[t] = v;
  __syncthreads();
  for (int off = 1; off < 256; off <<= 1) {
    unsigned add = (t >= off) ? s[t - off] : 0u;
    __syncthreads();
    s[t] += add;
    __syncthreads();
  }
  if (i < N_NODES) rowptr[i] = s[t] - v;  // exclusive
  if (t == 255) bsum[blockIdx.x] = s[255];
}

__global__ __launch_bounds__(512) void scan2_kernel(unsigned* __restrict__ bsum) {
  __shared__ unsigned s[512];
  int t = threadIdx.x;
  unsigned v = (t < NBLK) ? bsum[t] : 0u;
  s[t] = v;
  __syncthreads();
  for (int off = 1; off < 512; off <<= 1) {
    unsigned add = (t >= off) ? s[t - off] : 0u;
    __syncthreads();
    s[t] += add;
    __syncthreads();
  }
  if (t < NBLK) bsum[t] = s[t] - v;  // exclusive
}

__global__ __launch_bounds__(256) void scan3_kernel(unsigned* __restrict__ rowptr,
                                                    const unsigned* __restrict__ bsum) {
  int i = blockIdx.x * 256 + threadIdx.x;
  if (i < N_NODES) rowptr[i] += bsum[blockIdx.x];
  if (i == 0) rowptr[N_NODES] = ETOT;
}

// uses deg as a countdown cursor (deg ends at 0; row fill order is arbitrary)
__global__ __launch_bounds__(256) void scatter_kernel(const int* __restrict__ ei,
                                                      const unsigned* __restrict__ rowptr,
                                                      unsigned* __restrict__ deg,
                                                      int* __restrict__ csr_src) {
  int e = blockIdx.x * blockDim.x + threadIdx.x;
  if (e >= ETOT) return;
  int src, dst;
  if (e < E_EDGES) { src = ei[e]; dst = ei[E_EDGES + e]; }
  else { src = e - E_EDGES; dst = src; }
  unsigned pos = rowptr[dst] + atomicSub(&deg[dst], 1u) - 1u;
  csr_src[pos] = src;
}

// ===== GEMM1: x[N,128] @ W1l,W1r[128,128] (+bias) -> xl(fp16), xr(fp32) =====
__global__ __launch_bounds__(256) void gemm1_kernel(
    const float* __restrict__ x,
    const float* __restrict__ Wl, const float* __restrict__ bl,
    const float* __restrict__ Wr, const float* __restrict__ br,
    __half* __restrict__ xlh, float* __restrict__ xr) {
  __shared__ __align__(16) float xs[8][128];
  int t = threadIdx.x;
  int base = blockIdx.x * 8;
  for (int idx = t; idx < 8 * 128; idx += 256) {
    int r = idx >> 7, k = idx & 127;
    int row = base + r;
    xs[r][k] = (row < N_NODES) ? x[(size_t)row * 128 + k] : 0.f;
  }
  __syncthreads();
  bool isL = t < 128;
  const float* W = isL ? Wl : Wr;
  int col = t & 127;
  float bv = isL ? bl[col] : br[col];
  float acc[8];
#pragma unroll
  for (int r = 0; r < 8; r++) acc[r] = bv;
  for (int k4 = 0; k4 < 128; k4 += 4) {
    float w0 = W[(k4 + 0) * 128 + col];
    float w1 = W[(k4 + 1) * 128 + col];
    float w2 = W[(k4 + 2) * 128 + col];
    float w3 = W[(k4 + 3) * 128 + col];
#pragma unroll
    for (int r = 0; r < 8; r++) {
      float4 xv = *reinterpret_cast<const float4*>(&xs[r][k4]);
      acc[r] += xv.x * w0 + xv.y * w1 + xv.z * w2 + xv.w * w3;
    }
  }
#pragma unroll
  for (int r = 0; r < 8; r++) {
    int row = base + r;
    if (row < N_NODES) {
      if (isL) xlh[(size_t)row * 128 + col] = __float2half_rn(acc[r]);
      else xr[(size_t)row * 128 + col] = acc[r];
    }
  }
}

// ===== L1 fused gather: 1 wave/node, lane owns 2 ch, head = lane>>4, ILP2 =====
__global__ __launch_bounds__(256) void l1_gather_kernel(
    const __half2* __restrict__ xlh,   // [N][64] half2
    const float* __restrict__ xr,
    const int* __restrict__ csr_src, const unsigned* __restrict__ rowptr,
    const float* __restrict__ att, const float* __restrict__ bias,
    float* __restrict__ h1) {
  int wid = threadIdx.x >> 6;
  int lane = threadIdx.x & 63;
  int n = blockIdx.x * 4 + wid;
  if (n >= N_NODES) return;
  int c0 = lane * 2;
  float2 rv = *reinterpret_cast<const float2*>(xr + (size_t)n * 128 + c0);
  float2 av = *reinterpret_cast<const float2*>(att + c0);
  unsigned beg = rowptr[n], deg = rowptr[n + 1] - beg;
  float m0 = -1e30f, d0 = 0.f, x0 = 0.f, y0 = 0.f;
  float m1 = -1e30f, d1 = 0.f, x1 = 0.f, y1 = 0.f;
  for (unsigned base = 0; base < deg; base += 64) {
    unsigned cnt = min(64u, deg - base);
    int idx = (base + lane < deg) ? csr_src[beg + base + lane] : 0;
    unsigned k = 0;
    for (; k + 2 <= cnt; k += 2) {
      int s0 = __shfl(idx, (int)k);
      int s1 = __shfl(idx, (int)(k + 1));
      float2 a0 = __half22float2(xlh[(size_t)s0 * 64 + lane]);
      float2 a1 = __half22float2(xlh[(size_t)s1 * 64 + lane]);
      float v0 = av.x * lrelu(a0.x + rv.x) + av.y * lrelu(a0.y + rv.y);
      float v1 = av.x * lrelu(a1.x + rv.x) + av.y * lrelu(a1.y + rv.y);
      v0 += __shfl_xor(v0, 1);  v1 += __shfl_xor(v1, 1);
      v0 += __shfl_xor(v0, 2);  v1 += __shfl_xor(v1, 2);
      v0 += __shfl_xor(v0, 4);  v1 += __shfl_xor(v1, 4);
      v0 += __shfl_xor(v0, 8);  v1 += __shfl_xor(v1, 8);
      if (v0 > m0) { float s = __expf(m0 - v0); d0 *= s; x0 *= s; y0 *= s; m0 = v0; }
      float p0 = __expf(v0 - m0);
      d0 += p0; x0 += p0 * a0.x; y0 += p0 * a0.y;
      if (v1 > m1) { float s = __expf(m1 - v1); d1 *= s; x1 *= s; y1 *= s; m1 = v1; }
      float p1 = __expf(v1 - m1);
      d1 += p1; x1 += p1 * a1.x; y1 += p1 * a1.y;
    }
    if (k < cnt) {
      int s0 = __shfl(idx, (int)k);
      float2 a0 = __half22float2(xlh[(size_t)s0 * 64 + lane]);
      float v0 = av.x * lrelu(a0.x + rv.x) + av.y * lrelu(a0.y + rv.y);
      v0 += __shfl_xor(v0, 1);
      v0 += __shfl_xor(v0, 2);
      v0 += __shfl_xor(v0, 4);
      v0 += __shfl_xor(v0, 8);
      if (v0 > m0) { float s = __expf(m0 - v0); d0 *= s; x0 *= s; y0 *= s; m0 = v0; }
      float p0 = __expf(v0 - m0);
      d0 += p0; x0 += p0 * a0.x; y0 += p0 * a0.y;
    }
  }
  // merge the two states (state1 may be empty: e1 underflows to 0)
  float M = fmaxf(m0, m1);
  float e0 = __expf(m0 - M), e1 = __expf(m1 - M);
  float d = d0 * e0 + d1 * e1;
  float ax = x0 * e0 + x1 * e1;
  float ay = y0 * e0 + y1 * e1;
  float inv = 1.f / d;
  float2 res;
  res.x = elu(ax * inv + bias[c0]);
  res.y = elu(ay * inv + bias[c0 + 1]);
  *reinterpret_cast<float2*>(h1 + (size_t)n * 128 + c0) = res;
}

// ===== GEMM2: h1[N,128] @ W2l,W2r[128,32] (+bias) -> xl2(fp16), xr2(fp32) =====
__global__ __launch_bounds__(256) void gemm2_kernel(
    const float* __restrict__ h1,
    const float* __restrict__ Wl, const float* __restrict__ bl,
    const float* __restrict__ Wr, const float* __restrict__ br,
    __half* __restrict__ xl2h, float* __restrict__ xr2) {
  __shared__ __align__(16) float xs[4][128];
  int t = threadIdx.x;
  int base = blockIdx.x * 4;
  for (int idx = t; idx < 4 * 128; idx += 256) {
    int r = idx >> 7, k = idx & 127;
    int row = base + r;
    xs[r][k] = (row < N_NODES) ? h1[(size_t)row * 128 + k] : 0.f;
  }
  __syncthreads();
  int r = t >> 6, c6 = t & 63;
  bool isL = c6 < 32;
  int col = c6 & 31;
  const float* W = isL ? Wl : Wr;
  float acc = isL ? bl[col] : br[col];
  for (int k4 = 0; k4 < 128; k4 += 4) {
    float4 xv = *reinterpret_cast<const float4*>(&xs[r][k4]);
    acc += xv.x * W[(k4 + 0) * 32 + col] + xv.y * W[(k4 + 1) * 32 + col]
         + xv.z * W[(k4 + 2) * 32 + col] + xv.w * W[(k4 + 3) * 32 + col];
  }
  int row = base + r;
  if (row < N_NODES) {
    if (isL) xl2h[(size_t)row * 32 + col] = __float2half_rn(acc);
    else xr2[(size_t)row * 32 + col] = acc;
  }
}

// ===== L2 fused gather + final linear: 2 nodes/wave, 32 lanes/node =====
__global__ __launch_bounds__(256) void l2_gather_kernel(
    const __half* __restrict__ xl2h, const float* __restrict__ xr2,
    const int* __restrict__ csr_src, const unsigned* __restrict__ rowptr,
    const float* __restrict__ att, const float* __restrict__ bias,
    const float* __restrict__ Wlin, const float* __restrict__ blin,
    float* __restrict__ out) {
  int sub = threadIdx.x >> 5;      // 8 half-waves per block
  int lane = threadIdx.x & 31;
  int n = blockIdx.x * 8 + sub;
  if (n >= N_NODES) return;
  float rv = xr2[(size_t)n * 32 + lane];
  float avv = att[lane];
  unsigned beg = rowptr[n], deg = rowptr[n + 1] - beg;
  float m0 = -1e30f, d0 = 0.f, A0 = 0.f;
  float m1 = -1e30f, d1 = 0.f, A1 = 0.f;
  for (unsigned base = 0; base < deg; base += 32) {
    unsigned cnt = min(32u, deg - base);
    int idx = (base + lane < deg) ? csr_src[beg + base + lane] : 0;
    unsigned k = 0;
    for (; k + 2 <= cnt; k += 2) {
      int s0 = __shfl(idx, (int)k, 32);
      int s1 = __shfl(idx, (int)(k + 1), 32);
      float a0 = __half2float(xl2h[(size_t)s0 * 32 + lane]);
      float a1 = __half2float(xl2h[(size_t)s1 * 32 + lane]);
      float v0 = avv * lrelu(a0 + rv);
      float v1 = avv * lrelu(a1 + rv);
      v0 += __shfl_xor(v0, 1, 32);   v1 += __shfl_xor(v1, 1, 32);
      v0 += __shfl_xor(v0, 2, 32);   v1 += __shfl_xor(v1, 2, 32);
      v0 += __shfl_xor(v0, 4, 32);   v1 += __shfl_xor(v1, 4, 32);
      v0 += __shfl_xor(v0, 8, 32);   v1 += __shfl_xor(v1, 8, 32);
      v0 += __shfl_xor(v0, 16, 32);  v1 += __shfl_xor(v1, 16, 32);
      if (v0 > m0) { float s = __expf(m0 - v0); d0 *= s; A0 *= s; m0 = v0; }
      float p0 = __expf(v0 - m0);
      d0 += p0; A0 += p0 * a0;
      if (v1 > m1) { float s = __expf(m1 - v1); d1 *= s; A1 *= s; m1 = v1; }
      float p1 = __expf(v1 - m1);
      d1 += p1; A1 += p1 * a1;
    }
    if (k < cnt) {
      int s0 = __shfl(idx, (int)k, 32);
      float a0 = __half2float(xl2h[(size_t)s0 * 32 + lane]);
      float v0 = avv * lrelu(a0 + rv);
      v0 += __shfl_xor(v0, 1, 32);
      v0 += __shfl_xor(v0, 2, 32);
      v0 += __shfl_xor(v0, 4, 32);
      v0 += __shfl_xor(v0, 8, 32);
      v0 += __shfl_xor(v0, 16, 32);
      if (v0 > m0) { float s = __expf(m0 - v0); d0 *= s; A0 *= s; m0 = v0; }
      float p0 = __expf(v0 - m0);
      d0 += p0; A0 += p0 * a0;
    }
  }
  float M = fmaxf(m0, m1);
  float e0 = __expf(m0 - M), e1 = __expf(m1 - M);
  float d = d0 * e0 + d1 * e1;
  float acc = A0 * e0 + A1 * e1;
  float v = elu(acc / d + bias[lane]);
  float o0 = v * Wlin[lane * 2 + 0];
  float o1 = v * Wlin[lane * 2 + 1];
#pragma unroll
  for (int msk = 1; msk <= 16; msk <<= 1) {
    o0 += __shfl_xor(o0, msk, 32);
    o1 += __shfl_xor(o1, msk, 32);
  }
  if (lane == 0) {
    out[(size_t)n * 2 + 0] = o0 + blin[0];
    out[(size_t)n * 2 + 1] = o1 + blin[1];
  }
}

extern "C" void kernel_launch(void* const* d_in, const int* in_sizes, int n_in,
                              void* d_out, int out_size, void* d_ws, size_t ws_size,
                              hipStream_t stream) {
  const float* x     = (const float*)d_in[0];
  const int*   ei    = (const int*)d_in[1];
  const float* W1l   = (const float*)d_in[2];
  const float* b1l   = (const float*)d_in[3];
  const float* W1r   = (const float*)d_in[4];
  const float* b1r   = (const float*)d_in[5];
  const float* att1  = (const float*)d_in[6];
  const float* bias1 = (const float*)d_in[7];
  const float* W2l   = (const float*)d_in[8];
  const float* b2l   = (const float*)d_in[9];
  const float* W2r   = (const float*)d_in[10];
  const float* b2r   = (const float*)d_in[11];
  const float* att2  = (const float*)d_in[12];
  const float* bias2 = (const float*)d_in[13];
  const float* Wlin  = (const float*)d_in[14];
  const float* blin  = (const float*)d_in[15];
  float* out = (float*)d_out;

  // workspace layout:
  //   xl1h [N*128] half, xr1 [N*128] f32, h1 [N*128] f32,
  //   xl2h [N*32] half, xr2 [N*32] f32,
  //   csr_src [ETOT] int, rowptr [N+1] u32, deg [N] u32, bsum [512] u32
  __half* xl1h = (__half*)d_ws;
  float* xr1 = (float*)(xl1h + (size_t)N_NODES * 128);
  float* h1 = xr1 + (size_t)N_NODES * 128;
  __half* xl2h = (__half*)(h1 + (size_t)N_NODES * 128);
  float* xr2 = (float*)(xl2h + (size_t)N_NODES * 32);
  int* csr_src = (int*)(xr2 + (size_t)N_NODES * 32);
  unsigned* rowptr = (unsigned*)(csr_src + (size_t)ETOT);
  unsigned* deg = rowptr + (N_NODES + 1);
  unsigned* bsum = deg + N_NODES;

  // ---- CSR build (shared by both layers) ----
  hipMemsetAsync(deg, 0, (size_t)N_NODES * sizeof(unsigned), stream);
  hist_kernel<<<(ETOT + 255) / 256, 256, 0, stream>>>(ei, deg);
  scan1_kernel<<<NBLK, 256, 0, stream>>>(deg, rowptr, bsum);
  scan2_kernel<<<1, 512, 0, stream>>>(bsum);
  scan3_kernel<<<NBLK, 256, 0, stream>>>(rowptr, bsum);
  scatter_kernel<<<(ETOT + 255) / 256, 256, 0, stream>>>(ei, rowptr, deg, csr_src);

  // ---- layer 1 ----
  gemm1_kernel<<<(N_NODES + 7) / 8, 256, 0, stream>>>(x, W1l, b1l, W1r, b1r, xl1h, xr1);
  l1_gather_kernel<<<(N_NODES + 3) / 4, 256, 0, stream>>>(
      (const __half2*)xl1h, xr1, csr_src, rowptr, att1, bias1, h1);

  // ---- layer 2 + final linear ----
  gemm2_kernel<<<(N_NODES + 3) / 4, 256, 0, stream>>>(h1, W2l, b2l, W2r, b2r, xl2h, xr2);
  l2_gather_kernel<<<(N_NODES + 7) / 8, 256, 0, stream>>>(
      xl2h, xr2, csr_src, rowptr, att2, bias2, Wlin, blin, out);
}

// Round 4
// 443.997 us; speedup vs baseline: 34.1605x; 1.4071x over previous
//
#include <hip/hip_runtime.h>
#include <hip/hip_fp16.h>
#include <math.h>

#define N_NODES 100000
#define E_EDGES 1600000
#define ETOT (E_EDGES + N_NODES)   // 1,700,000 with self-loops appended
#define NEG 0.2f
#define NBLK ((N_NODES + 255) / 256)  // 391 scan blocks

typedef _Float16 half8 __attribute__((ext_vector_type(8)));
typedef float floatx4 __attribute__((ext_vector_type(4)));

__device__ __forceinline__ float lrelu(float v) { return v > 0.f ? v : NEG * v; }
__device__ __forceinline__ float elu(float v) { return v > 0.f ? v : (__expf(v) - 1.f); }

// ================= CSR build (by destination) =================
__global__ __launch_bounds__(256) void hist_kernel(const int* __restrict__ ei,
                                                   unsigned* __restrict__ deg) {
  int e = blockIdx.x * blockDim.x + threadIdx.x;
  if (e >= ETOT) return;
  int dst = (e < E_EDGES) ? ei[E_EDGES + e] : (e - E_EDGES);
  atomicAdd(&deg[dst], 1u);
}

__global__ __launch_bounds__(256) void scan1_kernel(const unsigned* __restrict__ deg,
                                                    unsigned* __restrict__ rowptr,
                                                    unsigned* __restrict__ bsum) {
  __shared__ unsigned s[256];
  int t = threadIdx.x;
  int i = blockIdx.x * 256 + t;
  unsigned v = (i < N_NODES) ? deg[i] : 0u;
  s[t] = v;
  __syncthreads();
  for (int off = 1; off < 256; off <<= 1) {
    unsigned add = (t >= off) ? s[t - off] : 0u;
    __syncthreads();
    s[t] += add;
    __syncthreads();
  }
  if (i < N_NODES) rowptr[i] = s[t] - v;  // exclusive
  if (t == 255) bsum[blockIdx.x] = s[255];
}

__global__ __launch_bounds__(512) void scan2_kernel(unsigned* __restrict__ bsum) {
  __shared__ unsigned s[512];
  int t = threadIdx.x;
  unsigned v = (t < NBLK) ? bsum[t] : 0u;
  s[t] = v;
  __syncthreads();
  for (int off = 1; off < 512; off <<= 1) {
    unsigned add = (t >= off) ? s[t - off] : 0u;
    __syncthreads();
    s[t] += add;
    __syncthreads();
  }
  if (t < NBLK) bsum[t] = s[t] - v;  // exclusive
}

__global__ __launch_bounds__(256) void scan3_kernel(unsigned* __restrict__ rowptr,
                                                    const unsigned* __restrict__ bsum) {
  int i = blockIdx.x * 256 + threadIdx.x;
  if (i < N_NODES) rowptr[i] += bsum[blockIdx.x];
  if (i == 0) rowptr[N_NODES] = ETOT;
}

// uses deg as a countdown cursor (deg ends at 0; row fill order is arbitrary)
__global__ __launch_bounds__(256) void scatter_kernel(const int* __restrict__ ei,
                                                      const unsigned* __restrict__ rowptr,
                                                      unsigned* __restrict__ deg,
                                                      int* __restrict__ csr_src) {
  int e = blockIdx.x * blockDim.x + threadIdx.x;
  if (e >= ETOT) return;
  int src, dst;
  if (e < E_EDGES) { src = ei[e]; dst = ei[E_EDGES + e]; }
  else { src = e - E_EDGES; dst = src; }
  unsigned pos = rowptr[dst] + atomicSub(&deg[dst], 1u) - 1u;
  csr_src[pos] = src;
}

// ================= prep: x -> fp16 =================
__global__ __launch_bounds__(256) void convert_x_kernel(const float4* __restrict__ xf4,
                                                        uint2* __restrict__ xh4) {
  int i = blockIdx.x * blockDim.x + threadIdx.x;
  if (i >= N_NODES * 128 / 4) return;
  float4 v = xf4[i];
  __half2 h0 = __floats2half2_rn(v.x, v.y);
  __half2 h1 = __floats2half2_rn(v.z, v.w);
  uint2 u;
  u.x = *(unsigned*)&h0;
  u.y = *(unsigned*)&h1;
  xh4[i] = u;
}

// ================= prep: pack W1/W2 into MFMA B-fragment layout + bias concat ===========
// Bperm1: 16 nt x 4 kt x 64 lane x 8 halves;  B2perm: 4 nt x 4 kt x 64 lane x 8
__global__ __launch_bounds__(256) void pack_w_kernel(
    const float* __restrict__ W1l, const float* __restrict__ W1r,
    const float* __restrict__ b1l, const float* __restrict__ b1r,
    const float* __restrict__ W2l, const float* __restrict__ W2r,
    const float* __restrict__ b2l, const float* __restrict__ b2r,
    _Float16* __restrict__ Bperm, _Float16* __restrict__ B2perm,
    float* __restrict__ biascat, float* __restrict__ bias2cat) {
  int t = threadIdx.x;
  for (int e = t; e < 4096; e += 256) {
    int nt = e >> 8, kt = (e >> 6) & 3, lane = e & 63;
    int n = nt * 16 + (lane & 15);
    int kb = kt * 32 + (lane >> 4) * 8;
#pragma unroll
    for (int j = 0; j < 8; j++) {
      int k = kb + j;
      float val = (n < 128) ? W1l[k * 128 + n] : W1r[k * 128 + (n - 128)];
      Bperm[(size_t)e * 8 + j] = (_Float16)val;
    }
  }
  for (int e = t; e < 1024; e += 256) {
    int nt = e >> 8, kt = (e >> 6) & 3, lane = e & 63;
    int n = nt * 16 + (lane & 15);
    int kb = kt * 32 + (lane >> 4) * 8;
#pragma unroll
    for (int j = 0; j < 8; j++) {
      int k = kb + j;
      float val = (n < 32) ? W2l[k * 32 + n] : W2r[k * 32 + (n - 32)];
      B2perm[(size_t)e * 8 + j] = (_Float16)val;
    }
  }
  if (t < 256) biascat[t] = (t < 128) ? b1l[t] : b1r[t - 128];
  if (t < 64) bias2cat[t] = (t < 32) ? b2l[t] : b2r[t - 32];
}

// ====== GEMM1 (MFMA): xh[N,128]f16 @ [128,256]f16 -> xl(fp16 cols 0-127), xr(fp32) ======
__global__ __launch_bounds__(256) void gemm1_mfma(
    const __half* __restrict__ xh, const _Float16* __restrict__ Bperm,
    const float* __restrict__ biascat,
    __half* __restrict__ xlh, float* __restrict__ xr) {
  __shared__ __align__(16) char smem[64 * 256];  // 64 rows x 128 f16, XOR-swizzled
  int t = threadIdx.x;
  int base = blockIdx.x * 64;
  {
    int row = t >> 2, c4 = t & 3;
    int grow = base + row;
    const char* gp = (const char*)(xh + (size_t)grow * 128 + c4 * 32);
#pragma unroll
    for (int j = 0; j < 4; j++) {
      half8 v = {};
      if (grow < N_NODES) v = *(const half8*)(gp + j * 16);
      int off = row * 256 + ((((c4 * 4 + j) * 16)) ^ ((row & 7) << 4));
      *(half8*)(smem + off) = v;
    }
  }
  int wid = t >> 6, lane = t & 63;
  half8 bf[4][4];  // [ntl][kt] — wave's 64 output cols
#pragma unroll
  for (int ntl = 0; ntl < 4; ntl++)
#pragma unroll
    for (int kt = 0; kt < 4; kt++) {
      int f = (wid * 4 + ntl) * 4 + kt;
      bf[ntl][kt] = *(const half8*)(Bperm + ((size_t)f * 64 + lane) * 8);
    }
  floatx4 acc[4][4] = {};  // [mt][ntl]
  __syncthreads();
#pragma unroll
  for (int kt = 0; kt < 4; kt++) {
    half8 a[4];
#pragma unroll
    for (int mt = 0; mt < 4; mt++) {
      int row = mt * 16 + (lane & 15);
      int kchunk = kt * 4 + (lane >> 4);
      int off = row * 256 + ((kchunk * 16) ^ ((row & 7) << 4));
      a[mt] = *(const half8*)(smem + off);
    }
#pragma unroll
    for (int mt = 0; mt < 4; mt++)
#pragma unroll
      for (int ntl = 0; ntl < 4; ntl++)
        acc[mt][ntl] = __builtin_amdgcn_mfma_f32_16x16x32_f16(a[mt], bf[ntl][kt],
                                                              acc[mt][ntl], 0, 0, 0);
  }
#pragma unroll
  for (int mt = 0; mt < 4; mt++) {
#pragma unroll
    for (int i = 0; i < 4; i++) {
      int row = base + mt * 16 + (lane >> 4) * 4 + i;
      if (row >= N_NODES) continue;
#pragma unroll
      for (int ntl = 0; ntl < 4; ntl++) {
        int col = wid * 64 + ntl * 16 + (lane & 15);
        float v = acc[mt][ntl][i] + biascat[col];
        if (col < 128) xlh[(size_t)row * 128 + col] = __float2half_rn(v);
        else xr[(size_t)row * 128 + (col - 128)] = v;
      }
    }
  }
}

// ====== GEMM2 (MFMA): h1[N,128]f16 @ [128,64]f16 -> xl2(fp16 cols 0-31), xr2(fp32) ======
__global__ __launch_bounds__(256) void gemm2_mfma(
    const __half* __restrict__ h1h, const _Float16* __restrict__ B2perm,
    const float* __restrict__ bias2cat,
    __half* __restrict__ xl2h, float* __restrict__ xr2) {
  __shared__ __align__(16) char smem[64 * 256];
  int t = threadIdx.x;
  int base = blockIdx.x * 64;
  {
    int row = t >> 2, c4 = t & 3;
    int grow = base + row;
    const char* gp = (const char*)(h1h + (size_t)grow * 128 + c4 * 32);
#pragma unroll
    for (int j = 0; j < 4; j++) {
      half8 v = {};
      if (grow < N_NODES) v = *(const half8*)(gp + j * 16);
      int off = row * 256 + ((((c4 * 4 + j) * 16)) ^ ((row & 7) << 4));
      *(half8*)(smem + off) = v;
    }
  }
  int wid = t >> 6, lane = t & 63;
  half8 bf[4];  // [kt]; wave owns 16 cols (nt = wid)
#pragma unroll
  for (int kt = 0; kt < 4; kt++) {
    int f = wid * 4 + kt;
    bf[kt] = *(const half8*)(B2perm + ((size_t)f * 64 + lane) * 8);
  }
  floatx4 acc[4] = {};  // [mt]
  __syncthreads();
#pragma unroll
  for (int kt = 0; kt < 4; kt++) {
    half8 a[4];
#pragma unroll
    for (int mt = 0; mt < 4; mt++) {
      int row = mt * 16 + (lane & 15);
      int kchunk = kt * 4 + (lane >> 4);
      int off = row * 256 + ((kchunk * 16) ^ ((row & 7) << 4));
      a[mt] = *(const half8*)(smem + off);
    }
#pragma unroll
    for (int mt = 0; mt < 4; mt++)
      acc[mt] = __builtin_amdgcn_mfma_f32_16x16x32_f16(a[mt], bf[kt], acc[mt], 0, 0, 0);
  }
  int col = wid * 16 + (lane & 15);
  float bv = bias2cat[col];
#pragma unroll
  for (int mt = 0; mt < 4; mt++) {
#pragma unroll
    for (int i = 0; i < 4; i++) {
      int row = base + mt * 16 + (lane >> 4) * 4 + i;
      if (row >= N_NODES) continue;
      float v = acc[mt][i] + bv;
      if (col < 32) xl2h[(size_t)row * 32 + col] = __float2half_rn(v);
      else xr2[(size_t)row * 32 + (col - 32)] = v;
    }
  }
}

// ===== L1 fused gather: 1 wave/node, lane owns 2 ch, head = lane>>4, ILP2 =====
__global__ __launch_bounds__(256) void l1_gather_kernel(
    const __half2* __restrict__ xlh,   // [N][64] half2
    const float* __restrict__ xr,
    const int* __restrict__ csr_src, const unsigned* __restrict__ rowptr,
    const float* __restrict__ att, const float* __restrict__ bias,
    __half* __restrict__ h1h) {
  int wid = threadIdx.x >> 6;
  int lane = threadIdx.x & 63;
  int n = blockIdx.x * 4 + wid;
  if (n >= N_NODES) return;
  int c0 = lane * 2;
  float2 rv = *reinterpret_cast<const float2*>(xr + (size_t)n * 128 + c0);
  float2 av = *reinterpret_cast<const float2*>(att + c0);
  unsigned beg = rowptr[n], deg = rowptr[n + 1] - beg;
  float m0 = -1e30f, d0 = 0.f, x0 = 0.f, y0 = 0.f;
  float m1 = -1e30f, d1 = 0.f, x1 = 0.f, y1 = 0.f;
  for (unsigned base = 0; base < deg; base += 64) {
    unsigned cnt = min(64u, deg - base);
    int idx = (base + lane < deg) ? csr_src[beg + base + lane] : 0;
    unsigned k = 0;
    for (; k + 2 <= cnt; k += 2) {
      int s0 = __shfl(idx, (int)k);
      int s1 = __shfl(idx, (int)(k + 1));
      float2 a0 = __half22float2(xlh[(size_t)s0 * 64 + lane]);
      float2 a1 = __half22float2(xlh[(size_t)s1 * 64 + lane]);
      float v0 = av.x * lrelu(a0.x + rv.x) + av.y * lrelu(a0.y + rv.y);
      float v1 = av.x * lrelu(a1.x + rv.x) + av.y * lrelu(a1.y + rv.y);
      v0 += __shfl_xor(v0, 1);  v1 += __shfl_xor(v1, 1);
      v0 += __shfl_xor(v0, 2);  v1 += __shfl_xor(v1, 2);
      v0 += __shfl_xor(v0, 4);  v1 += __shfl_xor(v1, 4);
      v0 += __shfl_xor(v0, 8);  v1 += __shfl_xor(v1, 8);
      if (v0 > m0) { float s = __expf(m0 - v0); d0 *= s; x0 *= s; y0 *= s; m0 = v0; }
      float p0 = __expf(v0 - m0);
      d0 += p0; x0 += p0 * a0.x; y0 += p0 * a0.y;
      if (v1 > m1) { float s = __expf(m1 - v1); d1 *= s; x1 *= s; y1 *= s; m1 = v1; }
      float p1 = __expf(v1 - m1);
      d1 += p1; x1 += p1 * a1.x; y1 += p1 * a1.y;
    }
    if (k < cnt) {
      int s0 = __shfl(idx, (int)k);
      float2 a0 = __half22float2(xlh[(size_t)s0 * 64 + lane]);
      float v0 = av.x * lrelu(a0.x + rv.x) + av.y * lrelu(a0.y + rv.y);
      v0 += __shfl_xor(v0, 1);
      v0 += __shfl_xor(v0, 2);
      v0 += __shfl_xor(v0, 4);
      v0 += __shfl_xor(v0, 8);
      if (v0 > m0) { float s = __expf(m0 - v0); d0 *= s; x0 *= s; y0 *= s; m0 = v0; }
      float p0 = __expf(v0 - m0);
      d0 += p0; x0 += p0 * a0.x; y0 += p0 * a0.y;
    }
  }
  float M = fmaxf(m0, m1);
  float e0 = __expf(m0 - M), e1 = __expf(m1 - M);
  float d = d0 * e0 + d1 * e1;
  float ax = x0 * e0 + x1 * e1;
  float ay = y0 * e0 + y1 * e1;
  float inv = 1.f / d;
  float rx = elu(ax * inv + bias[c0]);
  float ry = elu(ay * inv + bias[c0 + 1]);
  *reinterpret_cast<__half2*>(h1h + (size_t)n * 128 + c0) = __floats2half2_rn(rx, ry);
}

// ===== L2 fused gather + final linear: 2 nodes/wave, 32 lanes/node =====
__global__ __launch_bounds__(256) void l2_gather_kernel(
    const __half* __restrict__ xl2h, const float* __restrict__ xr2,
    const int* __restrict__ csr_src, const unsigned* __restrict__ rowptr,
    const float* __restrict__ att, const float* __restrict__ bias,
    const float* __restrict__ Wlin, const float* __restrict__ blin,
    float* __restrict__ out) {
  int sub = threadIdx.x >> 5;      // 8 half-waves per block
  int lane = threadIdx.x & 31;
  int n = blockIdx.x * 8 + sub;
  if (n >= N_NODES) return;
  float rv = xr2[(size_t)n * 32 + lane];
  float avv = att[lane];
  unsigned beg = rowptr[n], deg = rowptr[n + 1] - beg;
  float m0 = -1e30f, d0 = 0.f, A0 = 0.f;
  float m1 = -1e30f, d1 = 0.f, A1 = 0.f;
  for (unsigned base = 0; base < deg; base += 32) {
    unsigned cnt = min(32u, deg - base);
    int idx = (base + lane < deg) ? csr_src[beg + base + lane] : 0;
    unsigned k = 0;
    for (; k + 2 <= cnt; k += 2) {
      int s0 = __shfl(idx, (int)k, 32);
      int s1 = __shfl(idx, (int)(k + 1), 32);
      float a0 = __half2float(xl2h[(size_t)s0 * 32 + lane]);
      float a1 = __half2float(xl2h[(size_t)s1 * 32 + lane]);
      float v0 = avv * lrelu(a0 + rv);
      float v1 = avv * lrelu(a1 + rv);
      v0 += __shfl_xor(v0, 1, 32);   v1 += __shfl_xor(v1, 1, 32);
      v0 += __shfl_xor(v0, 2, 32);   v1 += __shfl_xor(v1, 2, 32);
      v0 += __shfl_xor(v0, 4, 32);   v1 += __shfl_xor(v1, 4, 32);
      v0 += __shfl_xor(v0, 8, 32);   v1 += __shfl_xor(v1, 8, 32);
      v0 += __shfl_xor(v0, 16, 32);  v1 += __shfl_xor(v1, 16, 32);
      if (v0 > m0) { float s = __expf(m0 - v0); d0 *= s; A0 *= s; m0 = v0; }
      float p0 = __expf(v0 - m0);
      d0 += p0; A0 += p0 * a0;
      if (v1 > m1) { float s = __expf(m1 - v1); d1 *= s; A1 *= s; m1 = v1; }
      float p1 = __expf(v1 - m1);
      d1 += p1; A1 += p1 * a1;
    }
    if (k < cnt) {
      int s0 = __shfl(idx, (int)k, 32);
      float a0 = __half2float(xl2h[(size_t)s0 * 32 + lane]);
      float v0 = avv * lrelu(a0 + rv);
      v0 += __shfl_xor(v0, 1, 32);
      v0 += __shfl_xor(v0, 2, 32);
      v0 += __shfl_xor(v0, 4, 32);
      v0 += __shfl_xor(v0, 8, 32);
      v0 += __shfl_xor(v0, 16, 32);
      if (v0 > m0) { float s = __expf(m0 - v0); d0 *= s; A0 *= s; m0 = v0; }
      float p0 = __expf(v0 - m0);
      d0 += p0; A0 += p0 * a0;
    }
  }
  float M = fmaxf(m0, m1);
  float e0 = __expf(m0 - M), e1 = __expf(m1 - M);
  float d = d0 * e0 + d1 * e1;
  float acc = A0 * e0 + A1 * e1;
  float v = elu(acc / d + bias[lane]);
  float o0 = v * Wlin[lane * 2 + 0];
  float o1 = v * Wlin[lane * 2 + 1];
#pragma unroll
  for (int msk = 1; msk <= 16; msk <<= 1) {
    o0 += __shfl_xor(o0, msk, 32);
    o1 += __shfl_xor(o1, msk, 32);
  }
  if (lane == 0) {
    out[(size_t)n * 2 + 0] = o0 + blin[0];
    out[(size_t)n * 2 + 1] = o1 + blin[1];
  }
}

extern "C" void kernel_launch(void* const* d_in, const int* in_sizes, int n_in,
                              void* d_out, int out_size, void* d_ws, size_t ws_size,
                              hipStream_t stream) {
  const float* x     = (const float*)d_in[0];
  const int*   ei    = (const int*)d_in[1];
  const float* W1l   = (const float*)d_in[2];
  const float* b1l   = (const float*)d_in[3];
  const float* W1r   = (const float*)d_in[4];
  const float* b1r   = (const float*)d_in[5];
  const float* att1  = (const float*)d_in[6];
  const float* bias1 = (const float*)d_in[7];
  const float* W2l   = (const float*)d_in[8];
  const float* b2l   = (const float*)d_in[9];
  const float* W2r   = (const float*)d_in[10];
  const float* b2r   = (const float*)d_in[11];
  const float* att2  = (const float*)d_in[12];
  const float* bias2 = (const float*)d_in[13];
  const float* Wlin  = (const float*)d_in[14];
  const float* blin  = (const float*)d_in[15];
  float* out = (float*)d_out;

  // workspace layout
  __half* xh    = (__half*)d_ws;                       // N*128 f16
  __half* xl1h  = xh + (size_t)N_NODES * 128;          // N*128 f16
  float*  xr1   = (float*)(xl1h + (size_t)N_NODES * 128);  // N*128 f32
  __half* h1h   = (__half*)(xr1 + (size_t)N_NODES * 128);  // N*128 f16
  __half* xl2h  = h1h + (size_t)N_NODES * 128;         // N*32 f16
  float*  xr2   = (float*)(xl2h + (size_t)N_NODES * 32);   // N*32 f32
  _Float16* Bperm  = (_Float16*)(xr2 + (size_t)N_NODES * 32);  // 32768
  _Float16* B2perm = Bperm + 32768;                    // 8192
  float* biascat   = (float*)(B2perm + 8192);          // 256
  float* bias2cat  = biascat + 256;                    // 64
  int* csr_src     = (int*)(bias2cat + 64);            // ETOT
  unsigned* rowptr = (unsigned*)(csr_src + (size_t)ETOT);  // N+1
  unsigned* deg    = rowptr + (N_NODES + 1);           // N
  unsigned* bsum   = deg + N_NODES;                    // 512

  // ---- prep (independent of CSR) ----
  convert_x_kernel<<<(N_NODES * 128 / 4 + 255) / 256, 256, 0, stream>>>(
      (const float4*)x, (uint2*)xh);
  pack_w_kernel<<<1, 256, 0, stream>>>(W1l, W1r, b1l, b1r, W2l, W2r, b2l, b2r,
                                       Bperm, B2perm, biascat, bias2cat);

  // ---- CSR build (shared by both layers) ----
  hipMemsetAsync(deg, 0, (size_t)N_NODES * sizeof(unsigned), stream);
  hist_kernel<<<(ETOT + 255) / 256, 256, 0, stream>>>(ei, deg);
  scan1_kernel<<<NBLK, 256, 0, stream>>>(deg, rowptr, bsum);
  scan2_kernel<<<1, 512, 0, stream>>>(bsum);
  scan3_kernel<<<NBLK, 256, 0, stream>>>(rowptr, bsum);
  scatter_kernel<<<(ETOT + 255) / 256, 256, 0, stream>>>(ei, rowptr, deg, csr_src);

  // ---- layer 1 ----
  gemm1_mfma<<<(N_NODES + 63) / 64, 256, 0, stream>>>(xh, Bperm, biascat, xl1h, xr1);
  l1_gather_kernel<<<(N_NODES + 3) / 4, 256, 0, stream>>>(
      (const __half2*)xl1h, xr1, csr_src, rowptr, att1, bias1, h1h);

  // ---- layer 2 + final linear ----
  gemm2_mfma<<<(N_NODES + 63) / 64, 256, 0, stream>>>(h1h, B2perm, bias2cat, xl2h, xr2);
  l2_gather_kernel<<<(N_NODES + 7) / 8, 256, 0, stream>>>(
      xl2h, xr2, csr_src, rowptr, att2, bias2, Wlin, blin, out);
}

// Round 6
// 393.143 us; speedup vs baseline: 38.5793x; 1.1294x over previous
//
#include <hip/hip_runtime.h>
#include <hip/hip_fp16.h>
#include <math.h>

#define N_NODES 100000
#define E_EDGES 1600000
#define ETOT (E_EDGES + N_NODES)   // 1,700,000 with self-loops appended
#define NEG 0.2f
#define NBLK ((N_NODES + 255) / 256)  // 391 scan blocks

typedef _Float16 half8 __attribute__((ext_vector_type(8)));
typedef _Float16 half4v __attribute__((ext_vector_type(4)));
typedef _Float16 half2v __attribute__((ext_vector_type(2)));
typedef float floatx4 __attribute__((ext_vector_type(4)));

union H8 {
  half8 v;
  _Float16 e[8];
};

__device__ __forceinline__ float elu(float v) { return v > 0.f ? v : (__expf(v) - 1.f); }

// packed fp16 score: sum(att * leakyrelu(a + r)) -> float
__device__ __forceinline__ float score8(half8 a, half8 r, half8 av) {
  half8 t = a + r;
  t = __builtin_elementwise_max(t, t * (_Float16)NEG);
  half8 s8 = t * av;
  half4v s4 = __builtin_shufflevector(s8, s8, 0, 1, 2, 3) +
              __builtin_shufflevector(s8, s8, 4, 5, 6, 7);
  half2v s2 = __builtin_shufflevector(s4, s4, 0, 1) +
              __builtin_shufflevector(s4, s4, 2, 3);
  return (float)s2[0] + (float)s2[1];
}

// ================= CSR build (by destination) =================
__global__ __launch_bounds__(256) void hist_kernel(const int* __restrict__ ei,
                                                   unsigned* __restrict__ deg) {
  int e = blockIdx.x * blockDim.x + threadIdx.x;
  if (e >= ETOT) return;
  int dst = (e < E_EDGES) ? ei[E_EDGES + e] : (e - E_EDGES);
  atomicAdd(&deg[dst], 1u);
}

__global__ __launch_bounds__(256) void scan1_kernel(const unsigned* __restrict__ deg,
                                                    unsigned* __restrict__ rowptr,
                                                    unsigned* __restrict__ bsum) {
  __shared__ unsigned s[256];
  int t = threadIdx.x;
  int i = blockIdx.x * 256 + t;
  unsigned v = (i < N_NODES) ? deg[i] : 0u;
  s[t] = v;
  __syncthreads();
  for (int off = 1; off < 256; off <<= 1) {
    unsigned add = (t >= off) ? s[t - off] : 0u;
    __syncthreads();
    s[t] += add;
    __syncthreads();
  }
  if (i < N_NODES) rowptr[i] = s[t] - v;  // exclusive
  if (t == 255) bsum[blockIdx.x] = s[255];
}

__global__ __launch_bounds__(512) void scan2_kernel(unsigned* __restrict__ bsum) {
  __shared__ unsigned s[512];
  int t = threadIdx.x;
  unsigned v = (t < NBLK) ? bsum[t] : 0u;
  s[t] = v;
  __syncthreads();
  for (int off = 1; off < 512; off <<= 1) {
    unsigned add = (t >= off) ? s[t - off] : 0u;
    __syncthreads();
    s[t] += add;
    __syncthreads();
  }
  if (t < NBLK) bsum[t] = s[t] - v;  // exclusive
}

__global__ __launch_bounds__(256) void scan3_kernel(unsigned* __restrict__ rowptr,
                                                    const unsigned* __restrict__ bsum) {
  int i = blockIdx.x * 256 + threadIdx.x;
  if (i < N_NODES) rowptr[i] += bsum[blockIdx.x];
  if (i == 0) rowptr[N_NODES] = ETOT;
}

// uses deg as a countdown cursor (deg ends at 0; row fill order is arbitrary)
__global__ __launch_bounds__(256) void scatter_kernel(const int* __restrict__ ei,
                                                      const unsigned* __restrict__ rowptr,
                                                      unsigned* __restrict__ deg,
                                                      int* __restrict__ csr_src) {
  int e = blockIdx.x * blockDim.x + threadIdx.x;
  if (e >= ETOT) return;
  int src, dst;
  if (e < E_EDGES) { src = ei[e]; dst = ei[E_EDGES + e]; }
  else { src = e - E_EDGES; dst = src; }
  unsigned pos = rowptr[dst] + atomicSub(&deg[dst], 1u) - 1u;
  csr_src[pos] = src;
}

// ================= prep: x -> fp16 =================
__global__ __launch_bounds__(256) void convert_x_kernel(const float4* __restrict__ xf4,
                                                        uint2* __restrict__ xh4) {
  int i = blockIdx.x * blockDim.x + threadIdx.x;
  if (i >= N_NODES * 128 / 4) return;
  float4 v = xf4[i];
  __half2 h0 = __floats2half2_rn(v.x, v.y);
  __half2 h1 = __floats2half2_rn(v.z, v.w);
  uint2 u;
  u.x = *(unsigned*)&h0;
  u.y = *(unsigned*)&h1;
  xh4[i] = u;
}

// ======= prep: pack W1/W2 into MFMA B-fragment layout, att->fp16, bias concat =======
__global__ __launch_bounds__(256) void pack_w_kernel(
    const float* __restrict__ W1l, const float* __restrict__ W1r,
    const float* __restrict__ b1l, const float* __restrict__ b1r,
    const float* __restrict__ W2l, const float* __restrict__ W2r,
    const float* __restrict__ b2l, const float* __restrict__ b2r,
    const float* __restrict__ att1, const float* __restrict__ att2,
    _Float16* __restrict__ Bperm, _Float16* __restrict__ B2perm,
    float* __restrict__ biascat, float* __restrict__ bias2cat,
    _Float16* __restrict__ att1h, _Float16* __restrict__ att2h) {
  int gt = blockIdx.x * 256 + threadIdx.x;
  int gstr = gridDim.x * 256;
  for (int e = gt; e < 4096; e += gstr) {
    int nt = e >> 8, kt = (e >> 6) & 3, lane = e & 63;
    int n = nt * 16 + (lane & 15);
    int kb = kt * 32 + (lane >> 4) * 8;
#pragma unroll
    for (int j = 0; j < 8; j++) {
      int k = kb + j;
      float val = (n < 128) ? W1l[k * 128 + n] : W1r[k * 128 + (n - 128)];
      Bperm[(size_t)e * 8 + j] = (_Float16)val;
    }
  }
  for (int e = gt; e < 1024; e += gstr) {
    int nt = e >> 8, kt = (e >> 6) & 3, lane = e & 63;
    int n = nt * 16 + (lane & 15);
    int kb = kt * 32 + (lane >> 4) * 8;
#pragma unroll
    for (int j = 0; j < 8; j++) {
      int k = kb + j;
      float val = (n < 32) ? W2l[k * 32 + n] : W2r[k * 32 + (n - 32)];
      B2perm[(size_t)e * 8 + j] = (_Float16)val;
    }
  }
  if (blockIdx.x == 0) {
    int t = threadIdx.x;
    biascat[t] = (t < 128) ? b1l[t] : b1r[t - 128];
    if (t < 64) bias2cat[t] = (t < 32) ? b2l[t] : b2r[t - 32];
    if (t < 128) att1h[t] = (_Float16)att1[t];
    if (t < 32) att2h[t] = (_Float16)att2[t];
  }
}

// ====== GEMM1 (MFMA): xh[N,128]f16 @ [128,256]f16 -> xlh, xrh (both fp16) ======
__global__ __launch_bounds__(256) void gemm1_mfma(
    const __half* __restrict__ xh, const _Float16* __restrict__ Bperm,
    const float* __restrict__ biascat,
    __half* __restrict__ xlh, __half* __restrict__ xrh) {
  __shared__ __align__(16) char smem[64 * 256];  // 64 rows x 128 f16, XOR-swizzled
  int t = threadIdx.x;
  int base = blockIdx.x * 64;
  {
    int row = t >> 2, c4 = t & 3;
    int grow = base + row;
    const char* gp = (const char*)(xh + (size_t)grow * 128 + c4 * 32);
#pragma unroll
    for (int j = 0; j < 4; j++) {
      half8 v = {};
      if (grow < N_NODES) v = *(const half8*)(gp + j * 16);
      int off = row * 256 + ((((c4 * 4 + j) * 16)) ^ ((row & 7) << 4));
      *(half8*)(smem + off) = v;
    }
  }
  int wid = t >> 6, lane = t & 63;
  half8 bf[4][4];  // [ntl][kt]
#pragma unroll
  for (int ntl = 0; ntl < 4; ntl++)
#pragma unroll
    for (int kt = 0; kt < 4; kt++) {
      int f = (wid * 4 + ntl) * 4 + kt;
      bf[ntl][kt] = *(const half8*)(Bperm + ((size_t)f * 64 + lane) * 8);
    }
  floatx4 acc[4][4] = {};  // [mt][ntl]
  __syncthreads();
#pragma unroll
  for (int kt = 0; kt < 4; kt++) {
    half8 a[4];
#pragma unroll
    for (int mt = 0; mt < 4; mt++) {
      int row = mt * 16 + (lane & 15);
      int kchunk = kt * 4 + (lane >> 4);
      int off = row * 256 + ((kchunk * 16) ^ ((row & 7) << 4));
      a[mt] = *(const half8*)(smem + off);
    }
#pragma unroll
    for (int mt = 0; mt < 4; mt++)
#pragma unroll
      for (int ntl = 0; ntl < 4; ntl++)
        acc[mt][ntl] = __builtin_amdgcn_mfma_f32_16x16x32_f16(a[mt], bf[ntl][kt],
                                                              acc[mt][ntl], 0, 0, 0);
  }
#pragma unroll
  for (int mt = 0; mt < 4; mt++) {
#pragma unroll
    for (int i = 0; i < 4; i++) {
      int row = base + mt * 16 + (lane >> 4) * 4 + i;
      if (row >= N_NODES) continue;
#pragma unroll
      for (int ntl = 0; ntl < 4; ntl++) {
        int col = wid * 64 + ntl * 16 + (lane & 15);
        float v = acc[mt][ntl][i] + biascat[col];
        if (col < 128) xlh[(size_t)row * 128 + col] = __float2half_rn(v);
        else xrh[(size_t)row * 128 + (col - 128)] = __float2half_rn(v);
      }
    }
  }
}

// ====== GEMM2 (MFMA): h1[N,128]f16 @ [128,64]f16 -> xl2h, xr2h (fp16) ======
__global__ __launch_bounds__(256) void gemm2_mfma(
    const __half* __restrict__ h1h, const _Float16* __restrict__ B2perm,
    const float* __restrict__ bias2cat,
    __half* __restrict__ xl2h, __half* __restrict__ xr2h) {
  __shared__ __align__(16) char smem[64 * 256];
  int t = threadIdx.x;
  int base = blockIdx.x * 64;
  {
    int row = t >> 2, c4 = t & 3;
    int grow = base + row;
    const char* gp = (const char*)(h1h + (size_t)grow * 128 + c4 * 32);
#pragma unroll
    for (int j = 0; j < 4; j++) {
      half8 v = {};
      if (grow < N_NODES) v = *(const half8*)(gp + j * 16);
      int off = row * 256 + ((((c4 * 4 + j) * 16)) ^ ((row & 7) << 4));
      *(half8*)(smem + off) = v;
    }
  }
  int wid = t >> 6, lane = t & 63;
  half8 bf[4];  // [kt]
#pragma unroll
  for (int kt = 0; kt < 4; kt++) {
    int f = wid * 4 + kt;
    bf[kt] = *(const half8*)(B2perm + ((size_t)f * 64 + lane) * 8);
  }
  floatx4 acc[4] = {};
  __syncthreads();
#pragma unroll
  for (int kt = 0; kt < 4; kt++) {
    half8 a[4];
#pragma unroll
    for (int mt = 0; mt < 4; mt++) {
      int row = mt * 16 + (lane & 15);
      int kchunk = kt * 4 + (lane >> 4);
      int off = row * 256 + ((kchunk * 16) ^ ((row & 7) << 4));
      a[mt] = *(const half8*)(smem + off);
    }
#pragma unroll
    for (int mt = 0; mt < 4; mt++)
      acc[mt] = __builtin_amdgcn_mfma_f32_16x16x32_f16(a[mt], bf[kt], acc[mt], 0, 0, 0);
  }
  int col = wid * 16 + (lane & 15);
  float bv = bias2cat[col];
#pragma unroll
  for (int mt = 0; mt < 4; mt++) {
#pragma unroll
    for (int i = 0; i < 4; i++) {
      int row = base + mt * 16 + (lane >> 4) * 4 + i;
      if (row >= N_NODES) continue;
      float v = acc[mt][i] + bv;
      if (col < 32) xl2h[(size_t)row * 32 + col] = __float2half_rn(v);
      else xr2h[(size_t)row * 32 + (col - 32)] = __float2half_rn(v);
    }
  }
}

// ===== L1 fused gather: 1 wave/node; 4 edges/iter (16 lanes each, 8 ch/lane) =====
// no-max softmax: |score| <~ 6, exp(v) safe in fp32
__global__ __launch_bounds__(256) void l1_gather_kernel(
    const __half* __restrict__ xlh, const __half* __restrict__ xrh,
    const int* __restrict__ csr_src, const unsigned* __restrict__ rowptr,
    const _Float16* __restrict__ att1h, const float* __restrict__ bias,
    __half* __restrict__ h1h) {
  int wid = threadIdx.x >> 6;
  int lane = threadIdx.x & 63;
  int n = blockIdx.x * 4 + wid;
  if (n >= N_NODES) return;
  int g = lane >> 4;        // edge slot 0..3
  int q = lane & 15;        // channel slice: ch q*8 .. q*8+7 (head = q>>2)
  int c0 = q * 8;
  half8 rv = *(const half8*)(xrh + (size_t)n * 128 + c0);
  half8 av = *(const half8*)(att1h + c0);
  unsigned beg = rowptr[n], end = rowptr[n + 1];
  int nit = (int)(end - beg + 3) >> 2;
  float d = 0.f;
  float acc[8] = {0.f};
  for (int i = 0; i < nit; i++) {
    unsigned e = beg + i * 4 + g;
    bool valid = e < end;
    int s = csr_src[valid ? e : (end - 1)];
    H8 a;
    a.v = *(const half8*)(xlh + (size_t)s * 128 + c0);
    float v = score8(a.v, rv, av);
    v += __shfl_xor(v, 1);
    v += __shfl_xor(v, 2);
    float p = valid ? __expf(v) : 0.f;
    d += p;
#pragma unroll
    for (int j = 0; j < 8; j++) acc[j] = fmaf(p, (float)a.e[j], acc[j]);
  }
  // merge the 4 edge-slot groups (lane distance 16, 32)
#pragma unroll
  for (int msk = 16; msk <= 32; msk <<= 1) {
    d += __shfl_xor(d, msk);
#pragma unroll
    for (int j = 0; j < 8; j++) acc[j] += __shfl_xor(acc[j], msk);
  }
  if (g == 0) {
    float inv = 1.f / d;
    H8 res;
#pragma unroll
    for (int j = 0; j < 8; j++)
      res.e[j] = (_Float16)elu(acc[j] * inv + bias[c0 + j]);
    *(half8*)(h1h + (size_t)n * 128 + c0) = res.v;
  }
}

// ===== L2 fused gather + final linear: 1 wave/node; 16 edges/iter (4 lanes each) =====
__global__ __launch_bounds__(256) void l2_gather_kernel(
    const __half* __restrict__ xl2h, const __half* __restrict__ xr2h,
    const int* __restrict__ csr_src, const unsigned* __restrict__ rowptr,
    const _Float16* __restrict__ att2h, const float* __restrict__ bias,
    const float* __restrict__ Wlin, const float* __restrict__ blin,
    float* __restrict__ out) {
  int wid = threadIdx.x >> 6;
  int lane = threadIdx.x & 63;
  int n = blockIdx.x * 4 + wid;
  if (n >= N_NODES) return;
  int g = lane >> 2;        // edge slot 0..15
  int q = lane & 3;         // channel slice: ch q*8 .. q*8+7
  int c0 = q * 8;
  half8 rv = *(const half8*)(xr2h + (size_t)n * 32 + c0);
  half8 av = *(const half8*)(att2h + c0);
  unsigned beg = rowptr[n], end = rowptr[n + 1];
  int nit = (int)(end - beg + 15) >> 4;
  float d = 0.f;
  float acc[8] = {0.f};
  for (int i = 0; i < nit; i++) {
    unsigned e = beg + i * 16 + g;
    bool valid = e < end;
    int s = csr_src[valid ? e : (end - 1)];
    H8 a;
    a.v = *(const half8*)(xl2h + (size_t)s * 32 + c0);
    float v = score8(a.v, rv, av);
    v += __shfl_xor(v, 1);
    v += __shfl_xor(v, 2);
    float p = valid ? __expf(v) : 0.f;
    d += p;
#pragma unroll
    for (int j = 0; j < 8; j++) acc[j] = fmaf(p, (float)a.e[j], acc[j]);
  }
  // merge the 16 edge-slot groups (lane distance 4, 8, 16, 32)
#pragma unroll
  for (int msk = 4; msk <= 32; msk <<= 1) {
    d += __shfl_xor(d, msk);
#pragma unroll
    for (int j = 0; j < 8; j++) acc[j] += __shfl_xor(acc[j], msk);
  }
  float inv = 1.f / d;
  float o0 = 0.f, o1 = 0.f;
#pragma unroll
  for (int j = 0; j < 8; j++) {
    float v = elu(acc[j] * inv + bias[c0 + j]);
    o0 = fmaf(v, Wlin[(c0 + j) * 2 + 0], o0);
    o1 = fmaf(v, Wlin[(c0 + j) * 2 + 1], o1);
  }
  o0 += __shfl_xor(o0, 1); o1 += __shfl_xor(o1, 1);
  o0 += __shfl_xor(o0, 2); o1 += __shfl_xor(o1, 2);
  if (lane == 0) {
    out[(size_t)n * 2 + 0] = o0 + blin[0];
    out[(size_t)n * 2 + 1] = o1 + blin[1];
  }
}

extern "C" void kernel_launch(void* const* d_in, const int* in_sizes, int n_in,
                              void* d_out, int out_size, void* d_ws, size_t ws_size,
                              hipStream_t stream) {
  const float* x     = (const float*)d_in[0];
  const int*   ei    = (const int*)d_in[1];
  const float* W1l   = (const float*)d_in[2];
  const float* b1l   = (const float*)d_in[3];
  const float* W1r   = (const float*)d_in[4];
  const float* b1r   = (const float*)d_in[5];
  const float* att1  = (const float*)d_in[6];
  const float* bias1 = (const float*)d_in[7];
  const float* W2l   = (const float*)d_in[8];
  const float* b2l   = (const float*)d_in[9];
  const float* W2r   = (const float*)d_in[10];
  const float* b2r   = (const float*)d_in[11];
  const float* att2  = (const float*)d_in[12];
  const float* bias2 = (const float*)d_in[13];
  const float* Wlin  = (const float*)d_in[14];
  const float* blin  = (const float*)d_in[15];
  float* out = (float*)d_out;

  // workspace layout (all fp16 feature buffers)
  __half* xh    = (__half*)d_ws;                        // N*128
  __half* xl1h  = xh + (size_t)N_NODES * 128;           // N*128
  __half* xr1h  = xl1h + (size_t)N_NODES * 128;         // N*128
  __half* h1h   = xr1h + (size_t)N_NODES * 128;         // N*128
  __half* xl2h  = h1h + (size_t)N_NODES * 128;          // N*32
  __half* xr2h  = xl2h + (size_t)N_NODES * 32;          // N*32
  _Float16* Bperm  = (_Float16*)(xr2h + (size_t)N_NODES * 32);  // 32768
  _Float16* B2perm = Bperm + 32768;                     // 8192
  _Float16* att1h  = B2perm + 8192;                     // 128
  _Float16* att2h  = att1h + 128;                       // 32 (+pad)
  float* biascat   = (float*)(att2h + 32);              // 256
  float* bias2cat  = biascat + 256;                     // 64
  int* csr_src     = (int*)(bias2cat + 64);             // ETOT
  unsigned* rowptr = (unsigned*)(csr_src + (size_t)ETOT);  // N+1
  unsigned* deg    = rowptr + (N_NODES + 1);            // N
  unsigned* bsum   = deg + N_NODES;                     // 512

  // ---- prep (independent of CSR) ----
  convert_x_kernel<<<(N_NODES * 128 / 4 + 255) / 256, 256, 0, stream>>>(
      (const float4*)x, (uint2*)xh);
  pack_w_kernel<<<20, 256, 0, stream>>>(W1l, W1r, b1l, b1r, W2l, W2r, b2l, b2r,
                                        att1, att2, Bperm, B2perm, biascat, bias2cat,
                                        att1h, att2h);

  // ---- CSR build (shared by both layers) ----
  (void)hipMemsetAsync(deg, 0, (size_t)N_NODES * sizeof(unsigned), stream);
  hist_kernel<<<(ETOT + 255) / 256, 256, 0, stream>>>(ei, deg);
  scan1_kernel<<<NBLK, 256, 0, stream>>>(deg, rowptr, bsum);
  scan2_kernel<<<1, 512, 0, stream>>>(bsum);
  scan3_kernel<<<NBLK, 256, 0, stream>>>(rowptr, bsum);
  scatter_kernel<<<(ETOT + 255) / 256, 256, 0, stream>>>(ei, rowptr, deg, csr_src);

  // ---- layer 1 ----
  gemm1_mfma<<<(N_NODES + 63) / 64, 256, 0, stream>>>(xh, Bperm, biascat, xl1h, xr1h);
  l1_gather_kernel<<<(N_NODES + 3) / 4, 256, 0, stream>>>(
      (const __half*)xl1h, (const __half*)xr1h, csr_src, rowptr, att1h, bias1, h1h);

  // ---- layer 2 + final linear ----
  gemm2_mfma<<<(N_NODES + 63) / 64, 256, 0, stream>>>(h1h, B2perm, bias2cat, xl2h, xr2h);
  l2_gather_kernel<<<(N_NODES + 3) / 4, 256, 0, stream>>>(
      xl2h, xr2h, csr_src, rowptr, att2h, bias2, Wlin, blin, out);
}